// Round 1
// baseline (100.553 us; speedup 1.0000x reference)
//
#include <hip/hip_runtime.h>
#include <hip/hip_bf16.h>

#define HIDDEN 128

// Kernel 1: per-node dual projection.
// 32 lanes cooperate on one node: lane i loads x[node*128 + 4i .. +3] (float4),
// dots against W_src / W_dst quads, shuffle-reduces over 32 lanes.
__global__ void node_proj_kernel(const float* __restrict__ x,
                                 const float* __restrict__ W,
                                 float2* __restrict__ p,
                                 int n_nodes) {
    const int lane = threadIdx.x & 31;
    const int node = (int)((blockIdx.x * (unsigned)blockDim.x + threadIdx.x) >> 5);
    if (node >= n_nodes) return;

    const float4 xv = *(const float4*)(x + (size_t)node * HIDDEN + lane * 4);
    const float4 ws = *(const float4*)(W + lane * 4);
    const float4 wd = *(const float4*)(W + HIDDEN + lane * 4);

    float ps = xv.x * ws.x + xv.y * ws.y + xv.z * ws.z + xv.w * ws.w;
    float pd = xv.x * wd.x + xv.y * wd.y + xv.z * wd.z + xv.w * wd.w;

    #pragma unroll
    for (int off = 16; off > 0; off >>= 1) {
        ps += __shfl_down(ps, off, 32);
        pd += __shfl_down(pd, off, 32);
    }
    if (lane == 0) p[node] = make_float2(ps, pd);
}

// Kernel 2: per-edge gather-add. 4 edges per thread, vectorized index load
// and output store. p (800 KB) is L2-resident so gathers are cheap.
__global__ void edge_out_kernel(const int* __restrict__ src,
                                const int* __restrict__ dst,
                                const float2* __restrict__ p,
                                const float* __restrict__ b,
                                float* __restrict__ out,
                                int n_edges) {
    const int base = (int)(blockIdx.x * (unsigned)blockDim.x + threadIdx.x) * 4;
    if (base >= n_edges) return;
    const float bb = b[0];

    if (base + 3 < n_edges) {
        const int4 s = *(const int4*)(src + base);
        const int4 d = *(const int4*)(dst + base);
        float4 o;
        o.x = p[s.x].x + p[d.x].y + bb;
        o.y = p[s.y].x + p[d.y].y + bb;
        o.z = p[s.z].x + p[d.z].y + bb;
        o.w = p[s.w].x + p[d.w].y + bb;
        *(float4*)(out + base) = o;
    } else {
        for (int e = base; e < n_edges; ++e) {
            out[e] = p[src[e]].x + p[dst[e]].y + bb;
        }
    }
}

extern "C" void kernel_launch(void* const* d_in, const int* in_sizes, int n_in,
                              void* d_out, int out_size, void* d_ws, size_t ws_size,
                              hipStream_t stream) {
    const float* x   = (const float*)d_in[0];   // (n_nodes, 128) fp32
    const int*   ei  = (const int*)d_in[1];     // (2, n_edges) int32
    const float* W   = (const float*)d_in[2];   // (1, 256) fp32
    const float* b   = (const float*)d_in[3];   // (1,) fp32
    float* out = (float*)d_out;                 // (n_edges,) fp32

    const int n_nodes = in_sizes[0] / HIDDEN;
    const int n_edges = in_sizes[1] / 2;
    const int* src = ei;
    const int* dst = ei + n_edges;

    float2* p = (float2*)d_ws;  // n_nodes * 8 bytes = 800 KB

    // Kernel 1: 32 lanes/node, 8 nodes per 256-thread block.
    {
        const int nodes_per_block = 256 / 32;
        const int grid = (n_nodes + nodes_per_block - 1) / nodes_per_block;
        node_proj_kernel<<<grid, 256, 0, stream>>>(x, W, p, n_nodes);
    }

    // Kernel 2: 4 edges/thread.
    {
        const int threads = (n_edges + 3) / 4;
        const int grid = (threads + 255) / 256;
        edge_out_kernel<<<grid, 256, 0, stream>>>(src, dst, p, b, out, n_edges);
    }
}